// Round 7
// baseline (167.414 us; speedup 1.0000x reference)
//
#include <hip/hip_runtime.h>
#include <hip/hip_bf16.h>

// VQ-VAE quantization forward for MI355X (gfx950).
// outputs (concat in d_out, fp32): quantized_ [16*4096*256], commitment_loss [1], perplexity [1]
//
// R7: phase-split. vq_argmin (MFMA argmax -> indices) and vq_epilogue (streaming
// gather/write/loss) as separate kernels so each runs at its own occupancy instead
// of serializing inside one block (R3-R6 all plateaued at 54-55 us fused).

typedef _Float16 half8_t __attribute__((ext_vector_type(8)));
typedef _Float16 half4_t __attribute__((ext_vector_type(4)));
typedef float f32x4 __attribute__((ext_vector_type(4)));

static constexpr int kRows = 65536;   // N*T
static constexpr int kD = 256;
static constexpr int kM = 512;

typedef const unsigned int __attribute__((address_space(1)))* gas_t;
typedef unsigned int __attribute__((address_space(3)))* las_t;

// ---------------- prep: normalize codebook -> fp16 in MFMA B-fragment order, bias, zero hist/loss --------
// swz layout (halves): [group g=c>>4][ko=k>>5][lane = qd*16 + (c&15)][j = k&7], qd=(k>>3)&3.
// A wave's read at lane*16B yields B[k=ko*32+qd*8+j][n=g*16+ln] as mfma_f32_16x16x32_f16 wants.
__global__ void vq_prep(const float* __restrict__ emb, _Float16* __restrict__ swz,
                        float* __restrict__ bias, unsigned int* __restrict__ hist,
                        float* __restrict__ loss) {
    const int j = blockIdx.x;       // code row, 512 blocks
    const int lane = threadIdx.x;   // 64 threads = 1 wave
    float4 v = ((const float4*)(emb + j * kD))[lane];
    float ss = v.x * v.x + v.y * v.y + v.z * v.z + v.w * v.w;
    #pragma unroll
    for (int off = 32; off > 0; off >>= 1) ss += __shfl_xor(ss, off);
    const float scale = 1.0f / (sqrtf(ss) + 1e-4f);
    if (lane == 0) bias[j] = 0.5f * ss * scale * scale;
    half4_t h;
    h[0] = (_Float16)(v.x * scale);
    h[1] = (_Float16)(v.y * scale);
    h[2] = (_Float16)(v.z * scale);
    h[3] = (_Float16)(v.w * scale);
    const int k0 = lane * 4;        // this lane covers k0..k0+3 (within one 8-half j-chunk)
    const int ko = k0 >> 5;
    const int qd = (k0 >> 3) & 3;
    const int jj = k0 & 7;          // 0 or 4
    const int off_h = (j >> 4) * 4096 + ko * 512 + (qd * 16 + (j & 15)) * 8 + jj;
    *(half4_t*)(swz + off_h) = h;
    if (j == 0) {
        for (int b = lane; b < kM; b += 64) hist[b] = 0u;
        if (lane == 0) loss[0] = 0.0f;
    }
}

// ---------------- argmin kernel: fp16 MFMA scores, dbuf fine-vmcnt staging, writes idx + hist ----------
// 1024 blocks x 128 thr (2 waves); wave owns 32 rows (2 A-sets) so one ds_read_b128 feeds 2 MFMAs.
// 16 stages of 32 codes, double-buffered 2x16KB; LDS ~37KB -> 4 blocks/CU.
__global__ __launch_bounds__(128, 2) void vq_argmin(
    const float* __restrict__ x, const _Float16* __restrict__ bswz,
    const float* __restrict__ bias, unsigned int* __restrict__ hist,
    int* __restrict__ idx_out) {
    __shared__ _Float16 bb[2][32 * kD];     // 2 x 16384 B
    __shared__ float lbias[kM];             // 2048 B
    __shared__ unsigned int lhist[kM];      // 2048 B

    const int t = threadIdx.x;              // 0..127, 2 waves
    const int row0 = blockIdx.x * 64;
    const int wave = t >> 6;
    const int lane = t & 63;
    const int qd = lane >> 4;               // quad 0..3
    const int ln = lane & 15;

    #pragma unroll
    for (int b = t; b < kM; b += 128) { lhist[b] = 0u; lbias[b] = bias[b]; }

    // Two A-fragment sets, loaded once: set s covers rows row0 + wave*32 + s*16 + ln
    // A[m=ln][k=ko*32+qd*8+j], fp32->fp16 (divergent but one-time: ~16 instrs/thread)
    half8_t a[2][8];
    #pragma unroll
    for (int s = 0; s < 2; ++s) {
        const float* xr = x + (size_t)(row0 + wave * 32 + s * 16 + ln) * kD + qd * 8;
        #pragma unroll
        for (int ko = 0; ko < 8; ++ko) {
            const float4 v0 = *(const float4*)(xr + ko * 32);
            const float4 v1 = *(const float4*)(xr + ko * 32 + 4);
            half8_t h;
            h[0] = (_Float16)v0.x; h[1] = (_Float16)v0.y;
            h[2] = (_Float16)v0.z; h[3] = (_Float16)v0.w;
            h[4] = (_Float16)v1.x; h[5] = (_Float16)v1.y;
            h[6] = (_Float16)v1.z; h[7] = (_Float16)v1.w;
            a[s][ko] = h;
        }
    }

    // stage loader: 16 KB (codes 32*st..32*st+31), 128 thr x 8 chunks x 16 B, direct-to-LDS
    auto stage_load = [&](int st, int buf) {
        const _Float16* src = bswz + (size_t)st * 8192 + t * 8;
        _Float16* dst = &bb[buf][0] + t * 8;
        #pragma unroll
        for (int i = 0; i < 8; ++i)
            __builtin_amdgcn_global_load_lds((gas_t)(const void*)(src + i * 1024),
                                             (las_t)(void*)(dst + i * 1024), 16, 0, 0);
    };

    stage_load(0, 0);   // prologue

    // argmax over 512 codes in 16 stages of 32; score = x.e_norm - 0.5*||e_norm||^2 (bias in acc init)
    float bv[2][4] = {{-1e30f, -1e30f, -1e30f, -1e30f}, {-1e30f, -1e30f, -1e30f, -1e30f}};
    int bi[2][4] = {{0, 0, 0, 0}, {0, 0, 0, 0}};
    #pragma unroll 1
    for (int st = 0; st < 16; ++st) {
        if (st < 15) stage_load(st + 1, (st + 1) & 1);   // prefetch into idle buffer
        // wait only the OLDER 8 loads (stage st); prefetch stays in flight across barrier
        if (st == 0)       __asm__ __volatile__("s_waitcnt vmcnt(8) lgkmcnt(0)\ns_barrier" ::: "memory");
        else if (st < 15)  __asm__ __volatile__("s_waitcnt vmcnt(8)\ns_barrier" ::: "memory");
        else               __asm__ __volatile__("s_waitcnt vmcnt(0)\ns_barrier" ::: "memory");

        const _Float16* bbase = &bb[st & 1][0];
        #pragma unroll
        for (int sg = 0; sg < 2; ++sg) {
            const int c = st * 32 + sg * 16 + ln;
            const float bbias = lbias[c];
            f32x4 acc0 = {-bbias, -bbias, -bbias, -bbias};
            f32x4 acc1 = {-bbias, -bbias, -bbias, -bbias};
            const half8_t* bp = (const half8_t*)bbase + sg * 512 + lane;
            #pragma unroll
            for (int ko = 0; ko < 8; ++ko) {
                const half8_t bf = bp[ko * 64];   // one ds_read_b128 feeds TWO MFMAs
                acc0 = __builtin_amdgcn_mfma_f32_16x16x32_f16(a[0][ko], bf, acc0, 0, 0, 0);
                acc1 = __builtin_amdgcn_mfma_f32_16x16x32_f16(a[1][ko], bf, acc1, 0, 0, 0);
            }
            #pragma unroll
            for (int r = 0; r < 4; ++r) {         // D[m][n]: n=ln, m=qd*4+r
                if (acc0[r] > bv[0][r]) { bv[0][r] = acc0[r]; bi[0][r] = c; }
                if (acc1[r] > bv[1][r]) { bv[1][r] = acc1[r]; bi[1][r] = c; }
            }
        }
        // readers of bb[st&1] done before stage st+2 overwrites it
        if (st < 15) __asm__ __volatile__("s_barrier" ::: "memory");
    }

    // reduce over the 16 lanes of each quad (same rows, different code subsets)
    #pragma unroll
    for (int s = 0; s < 2; ++s) {
        #pragma unroll
        for (int r = 0; r < 4; ++r) {
            #pragma unroll
            for (int off = 1; off < 16; off <<= 1) {
                const float ov = __shfl_xor(bv[s][r], off);
                const int oi = __shfl_xor(bi[s][r], off);
                if (ov > bv[s][r] || (ov == bv[s][r] && oi < bi[s][r])) { bv[s][r] = ov; bi[s][r] = oi; }
            }
            if (ln == 0) {
                idx_out[row0 + wave * 32 + s * 16 + qd * 4 + r] = bi[s][r];
                atomicAdd(&lhist[bi[s][r]], 1u);
            }
        }
    }
    __syncthreads();

    // flush histogram (skip zero bins)
    #pragma unroll
    for (int b = t; b < kM; b += 128) {
        const unsigned int h = lhist[b];
        if (h) atomicAdd(&hist[b], h);
    }
}

// ---------------- epilogue kernel: pure streaming gather + write + loss ----------------
// 1024 blocks x 256 thr, 64 rows/block; x L3-hot, emb L2-hot, out write-bound.
__global__ __launch_bounds__(256) void vq_epilogue(
    const float* __restrict__ x, const float* __restrict__ emb,
    const int* __restrict__ idx, float* __restrict__ loss_accum,
    float* __restrict__ out) {
    __shared__ int li[64];
    __shared__ float lred[4];
    const int t = threadIdx.x;
    const int row0 = blockIdx.x * 64;
    if (t < 64) li[t] = idx[row0 + t];
    __syncthreads();

    float lsum = 0.0f;
    const float* xg = x + (size_t)row0 * kD;
    float* og = out + (size_t)row0 * kD;
    #pragma unroll
    for (int i = 0; i < 16; ++i) {
        const int g = t * 4 + i * 1024;
        const int r = g >> 8;                       // one row per wave per i -> q coalesced 1KB
        const float4 xv = *(const float4*)(xg + g);
        const float4 q = *(const float4*)(emb + (size_t)li[r] * kD + (g & 255));
        const float d0 = xv.x - q.x, d1 = xv.y - q.y, d2 = xv.z - q.z, d3 = xv.w - q.w;
        lsum += d0 * d0 + d1 * d1 + d2 * d2 + d3 * d3;
        float4 o;  // ((x + (q-x)) + q) / 2
        o.x = ((xv.x + (q.x - xv.x)) + q.x) * 0.5f;
        o.y = ((xv.y + (q.y - xv.y)) + q.y) * 0.5f;
        o.z = ((xv.z + (q.z - xv.z)) + q.z) * 0.5f;
        o.w = ((xv.w + (q.w - xv.w)) + q.w) * 0.5f;
        *(float4*)&og[g] = o;
    }
    #pragma unroll
    for (int off = 32; off > 0; off >>= 1) lsum += __shfl_xor(lsum, off);
    if ((t & 63) == 0) lred[t >> 6] = lsum;
    __syncthreads();
    if (t == 0) atomicAdd(loss_accum, lred[0] + lred[1] + lred[2] + lred[3]);
}

// ---------------- final: scalars ----------------
__global__ void vq_final(const unsigned int* __restrict__ hist,
                         const float* __restrict__ loss_accum,
                         float* __restrict__ out) {
    const int t = threadIdx.x;  // 256 threads
    __shared__ float sr[4];
    float s = 0.0f;
    for (int b = t; b < kM; b += 256) {
        const float p = (float)hist[b] * (1.0f / 65536.0f);
        s += p * logf(p + 1e-10f);
    }
    #pragma unroll
    for (int off = 32; off > 0; off >>= 1) s += __shfl_xor(s, off);
    if ((t & 63) == 0) sr[t >> 6] = s;
    __syncthreads();
    if (t == 0) {
        const float tot = sr[0] + sr[1] + sr[2] + sr[3];
        out[16777217] = expf(-tot);                           // perplexity
        out[16777216] = loss_accum[0] * (1.0f / 16777216.0f); // commitment loss
    }
}

extern "C" void kernel_launch(void* const* d_in, const int* in_sizes, int n_in,
                              void* d_out, int out_size, void* d_ws, size_t ws_size,
                              hipStream_t stream) {
    const float* x = (const float*)d_in[0];     // (16,4096,256) fp32
    const float* emb = (const float*)d_in[1];   // (512,256) fp32
    char* ws = (char*)d_ws;
    _Float16* bswz = (_Float16*)ws;                           // 262144 B
    float* bias = (float*)(ws + 262144);                      // 2048 B
    unsigned int* hist = (unsigned int*)(ws + 262144 + 2048); // 2048 B
    float* loss = (float*)(ws + 262144 + 4096);               // 64 B (pad)
    int* idx = (int*)(ws + 262144 + 4096 + 64);               // 262144 B
    float* out = (float*)d_out;

    vq_prep<<<kM, 64, 0, stream>>>(emb, bswz, bias, hist, loss);
    vq_argmin<<<kRows / 64, 128, 0, stream>>>(x, bswz, bias, hist, idx);
    vq_epilogue<<<kRows / 64, 256, 0, stream>>>(x, emb, idx, loss, out);
    vq_final<<<1, 256, 0, stream>>>(hist, loss, out);
}

// Round 8
// 152.892 us; speedup vs baseline: 1.0950x; 1.0950x over previous
//
#include <hip/hip_runtime.h>
#include <hip/hip_bf16.h>

// VQ-VAE quantization forward for MI355X (gfx950).
// outputs (concat in d_out, fp32): quantized_ [16*4096*256], commitment_loss [1], perplexity [1]
//
// R8: role swap. B (codebook) lives in REGISTERS (each of 8 waves holds 64 codes'
// MFMA B-fragments in 128 VGPRs); x streams through LDS once per block. The K-loop
// has no global->LDS->MFMA dependency at all (R3-R7's invariant 54us bottleneck).
// Argmax via u32-packed (score|code) + v_max_u32 butterflies.

typedef _Float16 half8_t __attribute__((ext_vector_type(8)));
typedef _Float16 half4_t __attribute__((ext_vector_type(4)));
typedef float f32x4 __attribute__((ext_vector_type(4)));

static constexpr int kRows = 65536;   // N*T
static constexpr int kD = 256;
static constexpr int kM = 512;
static constexpr int kSH = 264;       // padded halves per LDS x-row

// ---------------- prep: normalize codebook -> fp16 in MFMA B-fragment order, bias, zero hist/loss --------
// swz layout (halves): [group g=c>>4][ko=k>>5][lane = qd*16 + (c&15)][j = k&7], qd=(k>>3)&3.
// A wave's read at lane*16B yields B[k=ko*32+qd*8+j][n=g*16+ln] as mfma_f32_16x16x32_f16 wants.
__global__ void vq_prep(const float* __restrict__ emb, _Float16* __restrict__ swz,
                        float* __restrict__ bias, unsigned int* __restrict__ hist,
                        float* __restrict__ loss) {
    const int j = blockIdx.x;       // code row, 512 blocks
    const int lane = threadIdx.x;   // 64 threads = 1 wave
    float4 v = ((const float4*)(emb + j * kD))[lane];
    float ss = v.x * v.x + v.y * v.y + v.z * v.z + v.w * v.w;
    #pragma unroll
    for (int off = 32; off > 0; off >>= 1) ss += __shfl_xor(ss, off);
    const float scale = 1.0f / (sqrtf(ss) + 1e-4f);
    if (lane == 0) bias[j] = 0.5f * ss * scale * scale;
    half4_t h;
    h[0] = (_Float16)(v.x * scale);
    h[1] = (_Float16)(v.y * scale);
    h[2] = (_Float16)(v.z * scale);
    h[3] = (_Float16)(v.w * scale);
    const int k0 = lane * 4;        // this lane covers k0..k0+3 (within one 8-half j-chunk)
    const int ko = k0 >> 5;
    const int qd = (k0 >> 3) & 3;
    const int jj = k0 & 7;          // 0 or 4
    const int off_h = (j >> 4) * 4096 + ko * 512 + (qd * 16 + (j & 15)) * 8 + jj;
    *(half4_t*)(swz + off_h) = h;
    if (j == 0) {
        for (int b = lane; b < kM; b += 64) hist[b] = 0u;
        if (lane == 0) loss[0] = 0.0f;
    }
}

// ---------------- argmin: B-in-registers, x staged once, packed-u32 argmax ----------------
// 512 blocks x 512 thr (8 waves); block owns 128 rows (2 tiles of 64).
__global__ __launch_bounds__(512, 2) void vq_argmin(
    const float* __restrict__ x, const _Float16* __restrict__ bswz,
    const float* __restrict__ bias, unsigned int* __restrict__ hist,
    int* __restrict__ idx_out) {
    __shared__ _Float16 xs[2][64 * kSH];    // 2 x 33792 B
    __shared__ unsigned int red[8 * 128];   // 4096 B: per-wave best per row
    __shared__ unsigned int lhist[kM];      // 2048 B

    const int t = threadIdx.x;              // 0..511, 8 waves
    const int row0 = blockIdx.x * 128;
    const int wave = t >> 6;
    const int lane = t & 63;
    const int qd = lane >> 4;
    const int ln = lane & 15;

    lhist[t] = 0u;

    // B fragments for this wave's 64 codes (groups wave*4..wave*4+3), loaded ONCE.
    // bfrag[nt][ko]: lane holds B[k=ko*32+qd*8+j][n = wave*64+nt*16+ln]. 128 VGPRs.
    half8_t bfrag[4][8];
    #pragma unroll
    for (int nt = 0; nt < 4; ++nt)
        #pragma unroll
        for (int ko = 0; ko < 8; ++ko)
            bfrag[nt][ko] = *(const half8_t*)(bswz + (size_t)(wave * 4 + nt) * 4096 + ko * 512 + lane * 8);

    // acc init = 64 - 0.5*||e_norm||^2 for this lane's code per n-tile (score kept positive for u32 cmp)
    float binit[4];
    #pragma unroll
    for (int nt = 0; nt < 4; ++nt) binit[nt] = 64.0f - bias[wave * 64 + nt * 16 + ln];

    // stage x: 128 rows x 256 f32 -> fp16 into 2 LDS tiles (coalesced 32B reads per thread)
    {
        const float* xg = x + (size_t)row0 * kD;
        #pragma unroll
        for (int i = 0; i < 8; ++i) {
            const int fi = t * 8 + i * 4096;      // float index in 128x256 tile
            const float4 v0 = *(const float4*)(xg + fi);
            const float4 v1 = *(const float4*)(xg + fi + 4);
            const int r = fi >> 8, c = fi & 255;  // buf = i>>2 (r<64 iff i<4)
            half8_t h;
            h[0] = (_Float16)v0.x; h[1] = (_Float16)v0.y;
            h[2] = (_Float16)v0.z; h[3] = (_Float16)v0.w;
            h[4] = (_Float16)v1.x; h[5] = (_Float16)v1.y;
            h[6] = (_Float16)v1.z; h[7] = (_Float16)v1.w;
            *(half8_t*)&xs[r >> 6][(r & 63) * kSH + c] = h;
        }
    }
    __syncthreads();

    // score = x.e_norm - 0.5||e_norm||^2 + 64, packed: (f32 bits & ~511) | code, argmax = u32 max
    #pragma unroll 1
    for (int tile = 0; tile < 2; ++tile) {
        const _Float16* xb = &xs[tile][0];
        #pragma unroll
        for (int mt = 0; mt < 4; ++mt) {
            half8_t a[8];   // A[m = mt*16+ln][k = ko*32+qd*8+j]
            #pragma unroll
            for (int ko = 0; ko < 8; ++ko)
                a[ko] = *(const half8_t*)(xb + (mt * 16 + ln) * kSH + qd * 8 + ko * 32);
            unsigned int best[4] = {0u, 0u, 0u, 0u};
            #pragma unroll
            for (int nt = 0; nt < 4; ++nt) {
                f32x4 acc = {binit[nt], binit[nt], binit[nt], binit[nt]};
                #pragma unroll
                for (int ko = 0; ko < 8; ++ko)
                    acc = __builtin_amdgcn_mfma_f32_16x16x32_f16(a[ko], bfrag[nt][ko], acc, 0, 0, 0);
                const unsigned int code = wave * 64 + nt * 16 + ln;
                #pragma unroll
                for (int r = 0; r < 4; ++r) {     // D[m][n]: n=ln (code), m=qd*4+r
                    const unsigned int pk = (__float_as_uint(acc[r]) & 0xFFFFFE00u) | code;
                    best[r] = best[r] > pk ? best[r] : pk;
                }
            }
            #pragma unroll
            for (int off = 1; off < 16; off <<= 1) {
                #pragma unroll
                for (int r = 0; r < 4; ++r) {
                    const unsigned int o = (unsigned int)__shfl_xor((int)best[r], off);
                    best[r] = best[r] > o ? best[r] : o;
                }
            }
            if (ln == 0) {   // lanes qd=0..3 write rows mt*16+qd*4 .. +3
                uint4 v; v.x = best[0]; v.y = best[1]; v.z = best[2]; v.w = best[3];
                *(uint4*)&red[wave * 128 + tile * 64 + mt * 16 + qd * 4] = v;
            }
        }
    }
    __syncthreads();

    // cross-wave reduce (8 candidates per row) + idx write + histogram
    if (t < 128) {
        unsigned int m = red[t];
        #pragma unroll
        for (int w = 1; w < 8; ++w) {
            const unsigned int o = red[w * 128 + t];
            m = m > o ? m : o;
        }
        const int idx = (int)(m & 511u);
        idx_out[row0 + t] = idx;
        atomicAdd(&lhist[idx], 1u);
    }
    __syncthreads();
    {
        const unsigned int h = lhist[t];
        if (h) atomicAdd(&hist[t], h);
    }
}

// ---------------- epilogue kernel: pure streaming gather + write + loss ----------------
__global__ __launch_bounds__(256) void vq_epilogue(
    const float* __restrict__ x, const float* __restrict__ emb,
    const int* __restrict__ idx, float* __restrict__ loss_accum,
    float* __restrict__ out) {
    __shared__ int li[64];
    __shared__ float lred[4];
    const int t = threadIdx.x;
    const int row0 = blockIdx.x * 64;
    if (t < 64) li[t] = idx[row0 + t];
    __syncthreads();

    float lsum = 0.0f;
    const float* xg = x + (size_t)row0 * kD;
    float* og = out + (size_t)row0 * kD;
    #pragma unroll
    for (int i = 0; i < 16; ++i) {
        const int g = t * 4 + i * 1024;
        const int r = g >> 8;                       // one row per wave per i -> q coalesced 1KB
        const float4 xv = *(const float4*)(xg + g);
        const float4 q = *(const float4*)(emb + (size_t)li[r] * kD + (g & 255));
        const float d0 = xv.x - q.x, d1 = xv.y - q.y, d2 = xv.z - q.z, d3 = xv.w - q.w;
        lsum += d0 * d0 + d1 * d1 + d2 * d2 + d3 * d3;
        float4 o;  // ((x + (q-x)) + q) / 2
        o.x = ((xv.x + (q.x - xv.x)) + q.x) * 0.5f;
        o.y = ((xv.y + (q.y - xv.y)) + q.y) * 0.5f;
        o.z = ((xv.z + (q.z - xv.z)) + q.z) * 0.5f;
        o.w = ((xv.w + (q.w - xv.w)) + q.w) * 0.5f;
        *(float4*)&og[g] = o;
    }
    #pragma unroll
    for (int off = 32; off > 0; off >>= 1) lsum += __shfl_xor(lsum, off);
    if ((t & 63) == 0) lred[t >> 6] = lsum;
    __syncthreads();
    if (t == 0) atomicAdd(loss_accum, lred[0] + lred[1] + lred[2] + lred[3]);
}

// ---------------- final: scalars ----------------
__global__ void vq_final(const unsigned int* __restrict__ hist,
                         const float* __restrict__ loss_accum,
                         float* __restrict__ out) {
    const int t = threadIdx.x;  // 256 threads
    __shared__ float sr[4];
    float s = 0.0f;
    for (int b = t; b < kM; b += 256) {
        const float p = (float)hist[b] * (1.0f / 65536.0f);
        s += p * logf(p + 1e-10f);
    }
    #pragma unroll
    for (int off = 32; off > 0; off >>= 1) s += __shfl_xor(s, off);
    if ((t & 63) == 0) sr[t >> 6] = s;
    __syncthreads();
    if (t == 0) {
        const float tot = sr[0] + sr[1] + sr[2] + sr[3];
        out[16777217] = expf(-tot);                           // perplexity
        out[16777216] = loss_accum[0] * (1.0f / 16777216.0f); // commitment loss
    }
}

extern "C" void kernel_launch(void* const* d_in, const int* in_sizes, int n_in,
                              void* d_out, int out_size, void* d_ws, size_t ws_size,
                              hipStream_t stream) {
    const float* x = (const float*)d_in[0];     // (16,4096,256) fp32
    const float* emb = (const float*)d_in[1];   // (512,256) fp32
    char* ws = (char*)d_ws;
    _Float16* bswz = (_Float16*)ws;                           // 262144 B
    float* bias = (float*)(ws + 262144);                      // 2048 B
    unsigned int* hist = (unsigned int*)(ws + 262144 + 2048); // 2048 B
    float* loss = (float*)(ws + 262144 + 4096);               // 64 B (pad)
    int* idx = (int*)(ws + 262144 + 4096 + 64);               // 262144 B
    float* out = (float*)d_out;

    vq_prep<<<kM, 64, 0, stream>>>(emb, bswz, bias, hist, loss);
    vq_argmin<<<kRows / 128, 512, 0, stream>>>(x, bswz, bias, hist, idx);
    vq_epilogue<<<kRows / 64, 256, 0, stream>>>(x, emb, idx, loss, out);
    vq_final<<<1, 256, 0, stream>>>(hist, loss, out);
}